// Round 1
// 2486.265 us; speedup vs baseline: 1.3667x; 1.3667x over previous
//
#include <hip/hip_runtime.h>
#include <cstddef>
#include <cstdint>

// Problem dims (fixed by setup_inputs): B=4, L=2048, D=1024, H=16, dh=64.
#define D_MODEL 1024
#define NH      16
#define DH      64
#define BATCH   4
#define SEQ     2048
#define BL      (BATCH * SEQ)   // 8192 rows
#define BHEADS  (BATCH * NH)    // 64 (b,h) pairs
// Reference quirk: scale = 1/sqrt(batch) = 0.5
#define SCALE   0.5f

typedef unsigned short u16;
typedef __attribute__((ext_vector_type(8))) short bf16x8;  // 8 bf16 (4 VGPRs)
typedef __attribute__((ext_vector_type(4))) float f32x4;   // 4 fp32 acc

__device__ __forceinline__ u16 f2b(float x) {
  uint32_t u = __float_as_uint(x);
  u += 0x7fffu + ((u >> 16) & 1u);   // round-to-nearest-even
  return (u16)(u >> 16);
}
__device__ __forceinline__ float b2f(u16 h) {
  return __uint_as_float(((uint32_t)h) << 16);
}
__device__ __forceinline__ void split2(float x, u16& hi, u16& lo) {
  hi = f2b(x);
  lo = f2b(x - b2f(hi));
}
__device__ __forceinline__ f32x4 mfma16(bf16x8 a, bf16x8 b, f32x4 c) {
  return __builtin_amdgcn_mfma_f32_16x16x32_bf16(a, b, c, 0, 0, 0);
}

// ---------------------------------------------------------------------------
// Transpose+split weights: W[k][n] fp32 -> Wt_hi/lo[n][k] bf16. grid (32,32).
// ---------------------------------------------------------------------------
__global__ __launch_bounds__(256) void wsplit(const float* __restrict__ W,
                                              u16* __restrict__ Th,
                                              u16* __restrict__ Tl) {
  __shared__ float t[32][33];
  const int c = threadIdx.x & 31;
  const int r0 = threadIdx.x >> 5;
  const int kb = blockIdx.y * 32;
  const int nb = blockIdx.x * 32;
#pragma unroll
  for (int rr = 0; rr < 32; rr += 8)
    t[r0 + rr][c] = W[(size_t)(kb + r0 + rr) * D_MODEL + nb + c];
  __syncthreads();
#pragma unroll
  for (int rr = 0; rr < 32; rr += 8) {
    const int n = r0 + rr;
    u16 h, l;
    split2(t[c][n], h, l);
    Th[(size_t)(nb + n) * D_MODEL + kb + c] = h;
    Tl[(size_t)(nb + n) * D_MODEL + kb + c] = l;
  }
}

// ---------------------------------------------------------------------------
// Split-bf16 MFMA GEMM: C[M=8192][N=1024] = A[M][1024] * Bt[N][1024]^T + bias
// 128x128 tile, BK=32, 256 thr (4 waves, 2x2), 4x4 16x16x32 frags per wave.
// AMODE 0: A fp32 (split during LDS staging); 1: A pre-split bf16 hi/lo.
// OUTMODE 0: fp32 [M][1024]; 1: bf16 hi/lo head layout [B,H,L,DH];
//         2: bf16 hi/lo transposed head layout [B,H,DH,L] (for V).
// LDS layout per operand: [4 ksub][128 row][8 elem] -> quarter-wave b128 reads
// are 256B contiguous (conflict-free).
// ---------------------------------------------------------------------------
template <int AMODE, int OUTMODE>
__global__ __launch_bounds__(256) void gemm_split(
    const float* __restrict__ Af,
    const u16* __restrict__ Agh, const u16* __restrict__ Agl,
    const u16* __restrict__ Bgh, const u16* __restrict__ Bgl,
    const float* __restrict__ bias,
    float* __restrict__ outf, u16* __restrict__ oh, u16* __restrict__ ol) {
  __shared__ __align__(16) short smem[4 * 4096];
  short* Ash = smem;
  short* Asl = smem + 4096;
  short* Bsh = smem + 8192;
  short* Bsl = smem + 12288;

  const int tid = threadIdx.x;
  const int m0 = blockIdx.y * 128;
  const int n0 = blockIdx.x * 128;
  const int srow = tid >> 1;   // staging row 0..127
  const int khalf = tid & 1;   // staging k-half (16 elems)

  const int wid = tid >> 6;
  const int lane = tid & 63;
  const int wr = wid >> 1, wc = wid & 1;
  const int ks = lane >> 4, lr = lane & 15;

  float av[16];
  bf16x8 rah[2], ral[2], rbh[2], rbl[2];

  f32x4 acc[4][4];
#pragma unroll
  for (int i = 0; i < 4; ++i)
#pragma unroll
    for (int j = 0; j < 4; ++j) acc[i][j] = (f32x4){0.f, 0.f, 0.f, 0.f};

  auto LOADA = [&](int k0) {
    if constexpr (AMODE == 0) {
      const float4* pa = reinterpret_cast<const float4*>(
          &Af[(size_t)(m0 + srow) * D_MODEL + k0 + khalf * 16]);
#pragma unroll
      for (int i = 0; i < 4; ++i) {
        float4 t = pa[i];
        av[i * 4 + 0] = t.x; av[i * 4 + 1] = t.y;
        av[i * 4 + 2] = t.z; av[i * 4 + 3] = t.w;
      }
    } else {
      const bf16x8* ph = reinterpret_cast<const bf16x8*>(
          &Agh[(size_t)(m0 + srow) * D_MODEL + k0 + khalf * 16]);
      rah[0] = ph[0]; rah[1] = ph[1];
      const bf16x8* pl = reinterpret_cast<const bf16x8*>(
          &Agl[(size_t)(m0 + srow) * D_MODEL + k0 + khalf * 16]);
      ral[0] = pl[0]; ral[1] = pl[1];
    }
  };
  auto LOADB = [&](int k0) {
    const bf16x8* ph = reinterpret_cast<const bf16x8*>(
        &Bgh[(size_t)(n0 + srow) * D_MODEL + k0 + khalf * 16]);
    rbh[0] = ph[0]; rbh[1] = ph[1];
    const bf16x8* pl = reinterpret_cast<const bf16x8*>(
        &Bgl[(size_t)(n0 + srow) * D_MODEL + k0 + khalf * 16]);
    rbl[0] = pl[0]; rbl[1] = pl[1];
  };
  auto STORE = [&]() {
#pragma unroll
    for (int sub = 0; sub < 2; ++sub) {
      const int ko = (khalf * 2 + sub) * 1024 + srow * 8;
      if constexpr (AMODE == 0) {
        bf16x8 h8, l8;
#pragma unroll
        for (int e = 0; e < 8; ++e) {
          u16 h, l;
          split2(av[sub * 8 + e], h, l);
          h8[e] = (short)h; l8[e] = (short)l;
        }
        *reinterpret_cast<bf16x8*>(&Ash[ko]) = h8;
        *reinterpret_cast<bf16x8*>(&Asl[ko]) = l8;
      } else {
        *reinterpret_cast<bf16x8*>(&Ash[ko]) = rah[sub];
        *reinterpret_cast<bf16x8*>(&Asl[ko]) = ral[sub];
      }
      *reinterpret_cast<bf16x8*>(&Bsh[ko]) = rbh[sub];
      *reinterpret_cast<bf16x8*>(&Bsl[ko]) = rbl[sub];
    }
  };

  LOADA(0); LOADB(0);
#pragma unroll 1
  for (int k0 = 0; k0 < D_MODEL; k0 += 32) {
    if (k0) __syncthreads();
    STORE();
    __syncthreads();
    if (k0 + 32 < D_MODEL) { LOADA(k0 + 32); LOADB(k0 + 32); }

    bf16x8 fah[4], fal[4], fbh[4], fbl[4];
#pragma unroll
    for (int i = 0; i < 4; ++i) {
      const int o = ks * 1024 + (wr * 64 + i * 16 + lr) * 8;
      fah[i] = *reinterpret_cast<const bf16x8*>(&Ash[o]);
      fal[i] = *reinterpret_cast<const bf16x8*>(&Asl[o]);
    }
#pragma unroll
    for (int j = 0; j < 4; ++j) {
      const int o = ks * 1024 + (wc * 64 + j * 16 + lr) * 8;
      fbh[j] = *reinterpret_cast<const bf16x8*>(&Bsh[o]);
      fbl[j] = *reinterpret_cast<const bf16x8*>(&Bsl[o]);
    }
#pragma unroll
    for (int i = 0; i < 4; ++i)
#pragma unroll
      for (int j = 0; j < 4; ++j) {
        acc[i][j] = mfma16(fah[i], fbh[j], acc[i][j]);
        acc[i][j] = mfma16(fah[i], fbl[j], acc[i][j]);
        acc[i][j] = mfma16(fal[i], fbh[j], acc[i][j]);
      }
  }

#pragma unroll
  for (int i = 0; i < 4; ++i)
#pragma unroll
    for (int j = 0; j < 4; ++j)
#pragma unroll
      for (int r = 0; r < 4; ++r) {
        const int m = m0 + wr * 64 + i * 16 + (lane >> 4) * 4 + r;
        const int n = n0 + wc * 64 + j * 16 + lr;
        const float val = acc[i][j][r] + bias[n];
        if constexpr (OUTMODE == 0) {
          outf[(size_t)m * D_MODEL + n] = val;
        } else {
          u16 h, l;
          split2(val, h, l);
          const int b = m >> 11, sl = m & (SEQ - 1);
          const int hh = n >> 6, dh = n & 63;
          size_t idx;
          if constexpr (OUTMODE == 1)
            idx = ((size_t)(b * NH + hh) * SEQ + sl) * DH + dh;
          else
            idx = ((size_t)(b * NH + hh) * DH + dh) * SEQ + sl;
          oh[idx] = h; ol[idx] = l;
        }
      }
}

// ---------------------------------------------------------------------------
// Scores: per (b,h): S = Q K^T * SCALE via split-bf16 MFMA, no LDS (operands
// are L2-resident per head; kernel is S-write bound). 128x128 tile.
// grid (SEQ/128, SEQ/128, BHEADS)
// ---------------------------------------------------------------------------
__global__ __launch_bounds__(256) void scores_mfma(
    const u16* __restrict__ qh, const u16* __restrict__ ql,
    const u16* __restrict__ kh, const u16* __restrict__ kl,
    float* __restrict__ S) {
  const int bh = blockIdx.z;
  const size_t hb = (size_t)bh * SEQ * DH;
  const int tid = threadIdx.x;
  const int wid = tid >> 6, lane = tid & 63;
  const int wr = wid >> 1, wc = wid & 1;
  const int ks = lane >> 4, lr = lane & 15;
  const int m0 = blockIdx.y * 128, n0 = blockIdx.x * 128;

  f32x4 acc[4][4];
#pragma unroll
  for (int i = 0; i < 4; ++i)
#pragma unroll
    for (int j = 0; j < 4; ++j) acc[i][j] = (f32x4){0.f, 0.f, 0.f, 0.f};

#pragma unroll
  for (int k2 = 0; k2 < 2; ++k2) {
    const int ko = k2 * 32 + ks * 8;
    bf16x8 fah[4], fal[4], fbh[4], fbl[4];
#pragma unroll
    for (int i = 0; i < 4; ++i) {
      const size_t o = hb + (size_t)(m0 + wr * 64 + i * 16 + lr) * DH + ko;
      fah[i] = *reinterpret_cast<const bf16x8*>(&qh[o]);
      fal[i] = *reinterpret_cast<const bf16x8*>(&ql[o]);
    }
#pragma unroll
    for (int j = 0; j < 4; ++j) {
      const size_t o = hb + (size_t)(n0 + wc * 64 + j * 16 + lr) * DH + ko;
      fbh[j] = *reinterpret_cast<const bf16x8*>(&kh[o]);
      fbl[j] = *reinterpret_cast<const bf16x8*>(&kl[o]);
    }
#pragma unroll
    for (int i = 0; i < 4; ++i)
#pragma unroll
      for (int j = 0; j < 4; ++j) {
        acc[i][j] = mfma16(fah[i], fbh[j], acc[i][j]);
        acc[i][j] = mfma16(fah[i], fbl[j], acc[i][j]);
        acc[i][j] = mfma16(fal[i], fbh[j], acc[i][j]);
      }
  }

  const size_t sb = (size_t)bh * SEQ * SEQ;
#pragma unroll
  for (int i = 0; i < 4; ++i)
#pragma unroll
    for (int j = 0; j < 4; ++j)
#pragma unroll
      for (int r = 0; r < 4; ++r) {
        const int m = m0 + wr * 64 + i * 16 + (lane >> 4) * 4 + r;
        const int n = n0 + wc * 64 + j * 16 + lr;
        S[sb + (size_t)m * SEQ + n] = acc[i][j][r] * SCALE;
      }
}

// ---------------------------------------------------------------------------
// In-place row softmax over 2048 cols; one block (256 thr) per row. (proven)
// ---------------------------------------------------------------------------
__global__ __launch_bounds__(256) void softmax_rows(float* __restrict__ S) {
  float* row = S + (size_t)blockIdx.x * SEQ;
  const int tid = threadIdx.x;
  float4 x0 = ((const float4*)row)[tid];
  float4 x1 = ((const float4*)row)[tid + 256];

  float m = fmaxf(fmaxf(fmaxf(x0.x, x0.y), fmaxf(x0.z, x0.w)),
                  fmaxf(fmaxf(x1.x, x1.y), fmaxf(x1.z, x1.w)));
#pragma unroll
  for (int off = 32; off; off >>= 1) m = fmaxf(m, __shfl_xor(m, off));
  __shared__ float redm[4];
  __shared__ float reds[4];
  const int wave = tid >> 6, lane = tid & 63;
  if (lane == 0) redm[wave] = m;
  __syncthreads();
  m = fmaxf(fmaxf(redm[0], redm[1]), fmaxf(redm[2], redm[3]));

  x0.x = __expf(x0.x - m); x0.y = __expf(x0.y - m);
  x0.z = __expf(x0.z - m); x0.w = __expf(x0.w - m);
  x1.x = __expf(x1.x - m); x1.y = __expf(x1.y - m);
  x1.z = __expf(x1.z - m); x1.w = __expf(x1.w - m);

  float s = x0.x + x0.y + x0.z + x0.w + x1.x + x1.y + x1.z + x1.w;
#pragma unroll
  for (int off = 32; off; off >>= 1) s += __shfl_xor(s, off);
  if (lane == 0) reds[wave] = s;
  __syncthreads();
  s = reds[0] + reds[1] + reds[2] + reds[3];

  const float inv = 1.0f / s;
  x0.x *= inv; x0.y *= inv; x0.z *= inv; x0.w *= inv;
  x1.x *= inv; x1.y *= inv; x1.z *= inv; x1.w *= inv;
  ((float4*)row)[tid] = x0;
  ((float4*)row)[tid + 256] = x1;
}

// ---------------------------------------------------------------------------
// PV: per (b,h): O = P(2048x2048 fp32, converted on the fly) @ V; V pre-split
// and pre-transposed [B,H,DH,L]. Writes ctx as bf16 hi/lo [BL][D].
// 128(m)x64(n) per block, 4 waves each 32 rows. grid (SEQ/128, BHEADS)
// ---------------------------------------------------------------------------
__global__ __launch_bounds__(256) void pv_mfma(
    const float* __restrict__ P,
    const u16* __restrict__ vth, const u16* __restrict__ vtl,
    u16* __restrict__ ch, u16* __restrict__ cl) {
  const int bh = blockIdx.y;
  const int b = bh >> 4, h = bh & 15;
  const int m0 = blockIdx.x * 128;
  const int tid = threadIdx.x;
  const int wr = tid >> 6;
  const int lane = tid & 63;
  const int ks = lane >> 4, lr = lane & 15;
  const float* Ph = P + (size_t)bh * SEQ * SEQ;
  const u16* vh = vth + (size_t)bh * DH * SEQ;
  const u16* vl = vtl + (size_t)bh * DH * SEQ;

  f32x4 acc[2][4];
#pragma unroll
  for (int i = 0; i < 2; ++i)
#pragma unroll
    for (int j = 0; j < 4; ++j) acc[i][j] = (f32x4){0.f, 0.f, 0.f, 0.f};

#pragma unroll 1
  for (int k0 = 0; k0 < SEQ; k0 += 32) {
    bf16x8 pah[2], pal[2];
#pragma unroll
    for (int i = 0; i < 2; ++i) {
      const float4* ps = reinterpret_cast<const float4*>(
          &Ph[(size_t)(m0 + wr * 32 + i * 16 + lr) * SEQ + k0 + ks * 8]);
      float4 s0 = ps[0], s1 = ps[1];
      float xs[8] = {s0.x, s0.y, s0.z, s0.w, s1.x, s1.y, s1.z, s1.w};
      bf16x8 h8, l8;
#pragma unroll
      for (int e = 0; e < 8; ++e) {
        u16 hh_, ll_;
        split2(xs[e], hh_, ll_);
        h8[e] = (short)hh_; l8[e] = (short)ll_;
      }
      pah[i] = h8; pal[i] = l8;
    }
    bf16x8 fbh[4], fbl[4];
#pragma unroll
    for (int j = 0; j < 4; ++j) {
      const size_t o = (size_t)(j * 16 + lr) * SEQ + k0 + ks * 8;
      fbh[j] = *reinterpret_cast<const bf16x8*>(&vh[o]);
      fbl[j] = *reinterpret_cast<const bf16x8*>(&vl[o]);
    }
#pragma unroll
    for (int i = 0; i < 2; ++i)
#pragma unroll
      for (int j = 0; j < 4; ++j) {
        acc[i][j] = mfma16(pah[i], fbh[j], acc[i][j]);
        acc[i][j] = mfma16(pah[i], fbl[j], acc[i][j]);
        acc[i][j] = mfma16(pal[i], fbh[j], acc[i][j]);
      }
  }

#pragma unroll
  for (int i = 0; i < 2; ++i)
#pragma unroll
    for (int j = 0; j < 4; ++j)
#pragma unroll
      for (int r = 0; r < 4; ++r) {
        const int gm = m0 + wr * 32 + i * 16 + (lane >> 4) * 4 + r;
        const int n = h * 64 + j * 16 + lr;
        u16 hh_, ll_;
        split2(acc[i][j][r], hh_, ll_);
        const size_t idx = (size_t)(b * SEQ + gm) * D_MODEL + n;
        ch[idx] = hh_; cl[idx] = ll_;
      }
}

// ---------------------------------------------------------------------------
extern "C" void kernel_launch(void* const* d_in, const int* in_sizes, int n_in,
                              void* d_out, int out_size, void* d_ws, size_t ws_size,
                              hipStream_t stream) {
  (void)in_sizes; (void)n_in; (void)out_size; (void)ws_size;
  const float* q  = (const float*)d_in[0];
  const float* k  = (const float*)d_in[1];
  const float* v  = (const float*)d_in[2];
  const float* Wq = (const float*)d_in[3];
  const float* bq = (const float*)d_in[4];
  const float* Wk = (const float*)d_in[5];
  const float* bk = (const float*)d_in[6];
  const float* Wv = (const float*)d_in[7];
  const float* bv = (const float*)d_in[8];
  const float* Wo = (const float*)d_in[9];
  const float* bo = (const float*)d_in[10];

  float* out  = (float*)d_out;                   // [B,L,D]
  float* attn = out + (size_t)BL * D_MODEL;      // [B,H,L,L]

  // Workspace (117.4 MB; previous version proved >=134 MB available):
  const size_t WSZ = (size_t)D_MODEL * D_MODEL;   // 1 MiB shorts per W half
  const size_t HSZ = (size_t)BHEADS * SEQ * DH;   // head tensor, shorts
  u16* ws16  = (u16*)d_ws;
  u16* WqT_h = ws16 + 0 * WSZ;
  u16* WqT_l = ws16 + 1 * WSZ;
  u16* WkT_h = ws16 + 2 * WSZ;
  u16* WkT_l = ws16 + 3 * WSZ;
  u16* WvT_h = ws16 + 4 * WSZ;
  u16* WvT_l = ws16 + 5 * WSZ;
  u16* WoT_h = ws16 + 6 * WSZ;
  u16* WoT_l = ws16 + 7 * WSZ;
  u16* base  = ws16 + 8 * WSZ;
  u16* qw_h  = base + 0 * HSZ;
  u16* qw_l  = base + 1 * HSZ;
  u16* kw_h  = base + 2 * HSZ;
  u16* kw_l  = base + 3 * HSZ;
  u16* vt_h  = base + 4 * HSZ;
  u16* vt_l  = base + 5 * HSZ;
  u16* ctx_h = qw_h;   // qw dead after scores; PV runs later (stream-ordered)
  u16* ctx_l = qw_l;

  const dim3 blk(256);
  const dim3 gw(32, 32);
  wsplit<<<gw, blk, 0, stream>>>(Wq, WqT_h, WqT_l);
  wsplit<<<gw, blk, 0, stream>>>(Wk, WkT_h, WkT_l);
  wsplit<<<gw, blk, 0, stream>>>(Wv, WvT_h, WvT_l);
  wsplit<<<gw, blk, 0, stream>>>(Wo, WoT_h, WoT_l);

  const dim3 gp(D_MODEL / 128, BL / 128);        // (8, 64)
  gemm_split<0, 1><<<gp, blk, 0, stream>>>(q, nullptr, nullptr, WqT_h, WqT_l,
                                           bq, nullptr, qw_h, qw_l);
  gemm_split<0, 1><<<gp, blk, 0, stream>>>(k, nullptr, nullptr, WkT_h, WkT_l,
                                           bk, nullptr, kw_h, kw_l);
  gemm_split<0, 2><<<gp, blk, 0, stream>>>(v, nullptr, nullptr, WvT_h, WvT_l,
                                           bv, nullptr, vt_h, vt_l);

  const dim3 gs(SEQ / 128, SEQ / 128, BHEADS);   // (16, 16, 64)
  scores_mfma<<<gs, blk, 0, stream>>>(qw_h, qw_l, kw_h, kw_l, attn);

  softmax_rows<<<dim3(BHEADS * SEQ), blk, 0, stream>>>(attn);

  const dim3 gpv(SEQ / 128, BHEADS);             // (16, 64)
  pv_mfma<<<gpv, blk, 0, stream>>>(attn, vt_h, vt_l, ctx_h, ctx_l);

  gemm_split<1, 0><<<gp, blk, 0, stream>>>(nullptr, ctx_h, ctx_l, WoT_h, WoT_l,
                                           bo, out, nullptr, nullptr);
}